// Round 1
// baseline (159.516 us; speedup 1.0000x reference)
//
#include <hip/hip_runtime.h>

#define BLOCK 256
#define GRID 2048

__global__ __launch_bounds__(BLOCK) void wbce_reduce_kernel(
    const float* __restrict__ x, const int* __restrict__ t,
    long long n, double* __restrict__ ws) {
    const long long n4 = n >> 2;
    long long idx = (long long)blockIdx.x * blockDim.x + threadIdx.x;
    const long long stride = (long long)gridDim.x * blockDim.x;

    float pos = 0.0f, neg = 0.0f;
    int cnt = 0;

    const float4* __restrict__ x4 = (const float4*)x;
    const int4*   __restrict__ t4 = (const int4*)t;

    for (long long i = idx; i < n4; i += stride) {
        float4 xv = x4[i];
        int4   tv = t4[i];
#define PROC(XC, TC)                                        \
        {                                                   \
            float xi = (XC); int ti = (TC);                 \
            float a = ti ? xi : (1.0f - xi);                \
            float v = -__logf(a);                           \
            pos += ti ? v : 0.0f;                           \
            neg += ti ? 0.0f : v;                           \
            cnt += ti ? 1 : 0;                              \
        }
        PROC(xv.x, tv.x)
        PROC(xv.y, tv.y)
        PROC(xv.z, tv.z)
        PROC(xv.w, tv.w)
#undef PROC
    }

    // scalar tail (n not divisible by 4) — handled by block 0 thread 0
    if (blockIdx.x == 0 && threadIdx.x == 0) {
        for (long long i = n4 << 2; i < n; ++i) {
            float xi = x[i]; int ti = t[i];
            float a = ti ? xi : (1.0f - xi);
            float v = -__logf(a);
            pos += ti ? v : 0.0f;
            neg += ti ? 0.0f : v;
            cnt += ti ? 1 : 0;
        }
    }

    // wave reduction (64 lanes)
    for (int o = 32; o > 0; o >>= 1) {
        pos += __shfl_down(pos, o);
        neg += __shfl_down(neg, o);
        cnt += __shfl_down(cnt, o);
    }

    __shared__ float s_pos[BLOCK / 64];
    __shared__ float s_neg[BLOCK / 64];
    __shared__ int   s_cnt[BLOCK / 64];
    const int lane = threadIdx.x & 63;
    const int wave = threadIdx.x >> 6;
    if (lane == 0) {
        s_pos[wave] = pos;
        s_neg[wave] = neg;
        s_cnt[wave] = cnt;
    }
    __syncthreads();

    if (threadIdx.x == 0) {
        double bpos = 0.0, bneg = 0.0;
        long long bcnt = 0;
        for (int w = 0; w < BLOCK / 64; ++w) {
            bpos += (double)s_pos[w];
            bneg += (double)s_neg[w];
            bcnt += s_cnt[w];
        }
        atomicAdd(&ws[0], (double)bcnt);
        atomicAdd(&ws[1], bpos);
        atomicAdd(&ws[2], bneg);
    }
}

__global__ void wbce_finalize_kernel(const double* __restrict__ ws,
                                     float* __restrict__ out, double n) {
    double s   = ws[0];
    double pos = ws[1];
    double neg = ws[2];
    double len = n + 1.0;
    double wp  = len / (s + 1.0);
    double wn  = len / (len - s);
    double loss = ((wp + 1.0) * pos + (wn + 1.0) * neg) / n;
    out[0] = (float)loss;
}

extern "C" void kernel_launch(void* const* d_in, const int* in_sizes, int n_in,
                              void* d_out, int out_size, void* d_ws, size_t ws_size,
                              hipStream_t stream) {
    const float* x = (const float*)d_in[0];
    const int*   t = (const int*)d_in[1];
    float* out = (float*)d_out;
    double* ws = (double*)d_ws;
    const long long n = (long long)in_sizes[0];

    hipMemsetAsync(ws, 0, 3 * sizeof(double), stream);
    wbce_reduce_kernel<<<GRID, BLOCK, 0, stream>>>(x, t, n, ws);
    wbce_finalize_kernel<<<1, 1, 0, stream>>>(ws, out, (double)n);
}

// Round 2
// 140.912 us; speedup vs baseline: 1.1320x; 1.1320x over previous
//
#include <hip/hip_runtime.h>

#define BLOCK 256
#define GRID 2048
#define UNROLL 4

__global__ __launch_bounds__(BLOCK) void wbce_reduce_kernel(
    const float* __restrict__ x, const int* __restrict__ t,
    long long n, double* __restrict__ ws) {
    const long long n4 = n >> 2;
    const long long idx = (long long)blockIdx.x * BLOCK + threadIdx.x;
    const long long stride = (long long)GRID * BLOCK;

    // tot = pos + neg; neg derived afterwards (saves one select+add per elem)
    float tot = 0.0f, pos = 0.0f;
    int cnt = 0;

    const float4* __restrict__ x4 = (const float4*)x;
    const int4*   __restrict__ t4 = (const int4*)t;

#define PROC(XC, TC)                                        \
    {                                                       \
        float xi = (XC); int ti = (TC);                     \
        float a = ti ? xi : (1.0f - xi);                    \
        float v = -__logf(a);                               \
        tot += v;                                           \
        pos += ti ? v : 0.0f;                               \
        cnt += ti ? 1 : 0;                                  \
    }

    const long long chunk = stride * UNROLL;
    const long long n4_main = n4 - (n4 % chunk);

    // main loop: 8 wide loads issued before any use -> 4x bytes in flight
    for (long long base = idx; base < n4_main; base += chunk) {
        float4 xv[UNROLL];
        int4   tv[UNROLL];
#pragma unroll
        for (int j = 0; j < UNROLL; ++j)
            xv[j] = x4[base + (long long)j * stride];
#pragma unroll
        for (int j = 0; j < UNROLL; ++j)
            tv[j] = t4[base + (long long)j * stride];
#pragma unroll
        for (int j = 0; j < UNROLL; ++j) {
            PROC(xv[j].x, tv[j].x)
            PROC(xv[j].y, tv[j].y)
            PROC(xv[j].z, tv[j].z)
            PROC(xv[j].w, tv[j].w)
        }
    }

    // remainder of float4-aligned region
    for (long long i = n4_main + idx; i < n4; i += stride) {
        float4 xv = x4[i];
        int4   tv = t4[i];
        PROC(xv.x, tv.x)
        PROC(xv.y, tv.y)
        PROC(xv.z, tv.z)
        PROC(xv.w, tv.w)
    }

    // scalar tail (n not divisible by 4) — block 0 thread 0
    if (idx == 0) {
        for (long long i = n4 << 2; i < n; ++i) {
            float xi = x[i]; int ti = t[i];
            float a = ti ? xi : (1.0f - xi);
            float v = -__logf(a);
            tot += v;
            pos += ti ? v : 0.0f;
            cnt += ti ? 1 : 0;
        }
    }
#undef PROC

    float neg = tot - pos;

    // wave reduction (64 lanes)
    for (int o = 32; o > 0; o >>= 1) {
        pos += __shfl_down(pos, o);
        neg += __shfl_down(neg, o);
        cnt += __shfl_down(cnt, o);
    }

    __shared__ float s_pos[BLOCK / 64];
    __shared__ float s_neg[BLOCK / 64];
    __shared__ int   s_cnt[BLOCK / 64];
    const int lane = threadIdx.x & 63;
    const int wave = threadIdx.x >> 6;
    if (lane == 0) {
        s_pos[wave] = pos;
        s_neg[wave] = neg;
        s_cnt[wave] = cnt;
    }
    __syncthreads();

    if (threadIdx.x == 0) {
        double bpos = 0.0, bneg = 0.0;
        long long bcnt = 0;
        for (int w = 0; w < BLOCK / 64; ++w) {
            bpos += (double)s_pos[w];
            bneg += (double)s_neg[w];
            bcnt += s_cnt[w];
        }
        atomicAdd(&ws[0], (double)bcnt);
        atomicAdd(&ws[1], bpos);
        atomicAdd(&ws[2], bneg);
    }
}

__global__ void wbce_finalize_kernel(const double* __restrict__ ws,
                                     float* __restrict__ out, double n) {
    double s   = ws[0];
    double pos = ws[1];
    double neg = ws[2];
    double len = n + 1.0;
    double wp  = len / (s + 1.0);
    double wn  = len / (len - s);
    double loss = ((wp + 1.0) * pos + (wn + 1.0) * neg) / n;
    out[0] = (float)loss;
}

extern "C" void kernel_launch(void* const* d_in, const int* in_sizes, int n_in,
                              void* d_out, int out_size, void* d_ws, size_t ws_size,
                              hipStream_t stream) {
    const float* x = (const float*)d_in[0];
    const int*   t = (const int*)d_in[1];
    float* out = (float*)d_out;
    double* ws = (double*)d_ws;
    const long long n = (long long)in_sizes[0];

    hipMemsetAsync(ws, 0, 3 * sizeof(double), stream);
    wbce_reduce_kernel<<<GRID, BLOCK, 0, stream>>>(x, t, n, ws);
    wbce_finalize_kernel<<<1, 1, 0, stream>>>(ws, out, (double)n);
}